// Round 5
// baseline (775.909 us; speedup 1.0000x reference)
//
#include <hip/hip_runtime.h>
#include <hip/hip_bf16.h>

#define B_ 8
#define C_ 96
#define H_ 256
#define W_ 256
#define HW_ (H_*W_)
#define EPSV 1e-5f

typedef _Float16 f16x8 __attribute__((ext_vector_type(8)));
typedef _Float16 f16x4 __attribute__((ext_vector_type(4)));
typedef float    f32x4 __attribute__((ext_vector_type(4)));

// ---------------------------------------------------------------------------
// K1: per-pixel LN stats, 4 pixels/thread via float4 loads.
// ---------------------------------------------------------------------------
__global__ __launch_bounds__(256) void k_stats(const float* __restrict__ fea,
                                               float4* __restrict__ stats4) {
    int p4 = blockIdx.x * 256 + threadIdx.x;   // pixel-quad index
    int b  = p4 >> 14;                          // 16384 quads per batch
    int r  = (p4 & 16383) * 4;
    const float* pp = fea + (size_t)b * C_ * HW_ + r;
    float s0=0,q0=0,s1=0,q1=0,s2=0,q2=0,s3=0,q3=0;
#pragma unroll 8
    for (int c = 0; c < C_; ++c) {
        float4 v = *(const float4*)(pp + (size_t)c * HW_);
        s0+=v.x; q0+=v.x*v.x; s1+=v.y; q1+=v.y*v.y;
        s2+=v.z; q2+=v.z*v.z; s3+=v.w; q3+=v.w*v.w;
    }
    const float inv = 1.0f / C_;
    float m0=s0*inv, m1=s1*inv, m2=s2*inv, m3=s3*inv;
    stats4[p4*2+0] = make_float4(m0, rsqrtf(q0*inv-m0*m0+EPSV),
                                 m1, rsqrtf(q1*inv-m1*m1+EPSV));
    stats4[p4*2+1] = make_float4(m2, rsqrtf(q2*inv-m2*m2+EPSV),
                                 m3, rsqrtf(q3*inv-m3*m3+EPSV));
}

// ---------------------------------------------------------------------------
// K2: wave-per-channel. Block = 4 waves = 4 channels of one 16x32 tile.
// Each wave: stage LN halo -> conv1(3x3) -> conv2(1x5, overlays xs) ->
// conv3(5x1) -> fp16 plane, all in private LDS slices, NO barriers.
// One __syncthreads, then transpose to [b][cg24][hw][4ch] fp16.
// ---------------------------------------------------------------------------
#define XD 44                  // LDS row stride (dwords)
#define XS_DW (22*XD)          // 968: xs = 22 rows x 38 cols
#define Y1_DW (20*XD)          // 880: y1 = 20 rows x 36 cols
#define WV_DW (XS_DW + Y1_DW)  // 1848 per wave

__global__ __launch_bounds__(256) void k_dw(
    const float* __restrict__ fea, const float2* __restrict__ stats,
    const float* __restrict__ gamma, const float* __restrict__ beta,
    const float* __restrict__ w1, const float* __restrict__ b1,
    const float* __restrict__ w2, const float* __restrict__ b2,
    const float* __restrict__ w3, const float* __restrict__ b3,
    _Float16* __restrict__ y3g)
{
    __shared__ __align__(16) float    lds[4 * WV_DW];   // 29568 B
    __shared__ __align__(16) _Float16 y3p[4][520];      //  4160 B

    const int tid  = threadIdx.x;
    const int wv   = tid >> 6, lane = tid & 63;
    const int bw0  = blockIdx.x * 32;
    const int bh0  = blockIdx.y * 16;
    const int z    = blockIdx.z;
    const int b    = z / 24, cg = z % 24;
    const int c    = cg * 4 + wv;

    float* xs = lds + wv * WV_DW;   // rows 0..21 = gh bh0-3..+18, cols 0..37 = gw bw0-3..+34
    float* y1 = xs + XS_DW;         // rows 0..19 = gh bh0-2..+17, cols 0..35 = gw bw0-2..+33
    float* y2 = xs;                 // overlay;  rows 0..19 = gh bh0-2..+17, cols 0..31 = gw bw0..+31

    const float2* stb  = stats + (size_t)b * HW_;
    const float*  feac = fea + ((size_t)b * C_ + c) * HW_;
    const float g = gamma[c], bt = beta[c];
    float w1v[9], w2v[5], w3v[5];
#pragma unroll
    for (int i = 0; i < 9; ++i) w1v[i] = w1[c * 9 + i];
#pragma unroll
    for (int i = 0; i < 5; ++i) w2v[i] = w2[c * 5 + i];
#pragma unroll
    for (int i = 0; i < 5; ++i) w3v[i] = w3[c * 5 + i];
    const float bb1 = b1[c], bb2 = b2[c], bb3 = b3[c];

    // ---- stage x = LN(fea) over 22x38 halo (0 outside image)
#pragma unroll 1
    for (int p = lane; p < 22 * 38; p += 64) {
        int r = p / 38, cc = p - 38 * r;
        int gh = bh0 - 3 + r, gw = bw0 - 3 + cc;
        float v = 0.f;
        if ((unsigned)gh < H_ && (unsigned)gw < W_) {
            float2 st = stb[(gh << 8) + gw];
            v = (feac[(gh << 8) + gw] - st.x) * st.y * g + bt;
        }
        xs[r * XD + cc] = v;
    }

    // ---- conv1 3x3: 20 rows x 9 groups of 4 cols (y1 cols 0..35)
#pragma unroll 1
    for (int t = lane; t < 180; t += 64) {
        int r1 = t / 9, gq = t - 9 * r1;
        int cb = 4 * gq;
        float4 a0 = *(const float4*)&xs[(r1 + 0) * XD + cb];
        float4 a1 = *(const float4*)&xs[(r1 + 0) * XD + cb + 4];
        float4 b0 = *(const float4*)&xs[(r1 + 1) * XD + cb];
        float4 b4 = *(const float4*)&xs[(r1 + 1) * XD + cb + 4];
        float4 c0 = *(const float4*)&xs[(r1 + 2) * XD + cb];
        float4 c4 = *(const float4*)&xs[(r1 + 2) * XD + cb + 4];
        float wnd[3][8] = {
            {a0.x,a0.y,a0.z,a0.w,a1.x,a1.y,a1.z,a1.w},
            {b0.x,b0.y,b0.z,b0.w,b4.x,b4.y,b4.z,b4.w},
            {c0.x,c0.y,c0.z,c0.w,c4.x,c4.y,c4.z,c4.w}};
        int gh = bh0 - 2 + r1;
        bool rin = (unsigned)gh < H_;
        float o[4];
#pragma unroll
        for (int k = 0; k < 4; ++k) {
            float s = bb1;
#pragma unroll
            for (int dr = 0; dr < 3; ++dr)
#pragma unroll
                for (int dj = 0; dj < 3; ++dj)
                    s += w1v[dr * 3 + dj] * wnd[dr][k + dj];
            int gw = bw0 - 2 + cb + k;
            o[k] = (rin && (unsigned)gw < W_) ? s : 0.f;
        }
        *(float4*)&y1[r1 * XD + cb] = make_float4(o[0], o[1], o[2], o[3]);
    }

    // ---- conv2 1x5: 20 rows x 8 groups of 4 cols (y2 cols 0..31)
#pragma unroll 1
    for (int t = lane; t < 160; t += 64) {
        int r2 = t >> 3, gq = t & 7;
        int cb = 4 * gq;
        float4 a = *(const float4*)&y1[r2 * XD + cb];
        float4 d = *(const float4*)&y1[r2 * XD + cb + 4];
        float wnd[8] = {a.x,a.y,a.z,a.w,d.x,d.y,d.z,d.w};
        int gh = bh0 - 2 + r2;
        bool rin = (unsigned)gh < H_;
        float o[4];
#pragma unroll
        for (int i = 0; i < 4; ++i) {
            float s = bb2;
#pragma unroll
            for (int j = 0; j < 5; ++j) s += w2v[j] * wnd[i + j];
            o[i] = rin ? s : 0.f;
        }
        *(float4*)&y2[r2 * XD + cb] = make_float4(o[0], o[1], o[2], o[3]);
    }

    // ---- conv3 5x1: 16 rows x 8 groups of 4 cols -> fp16 plane
#pragma unroll 1
    for (int t = lane; t < 128; t += 64) {
        int r3 = t >> 3, gq = t & 7;
        int cb = 4 * gq;
        float o0 = bb3, o1 = bb3, o2 = bb3, o3 = bb3;
#pragma unroll
        for (int dr = 0; dr < 5; ++dr) {
            float4 a = *(const float4*)&y2[(r3 + dr) * XD + cb];
            o0 += w3v[dr] * a.x; o1 += w3v[dr] * a.y;
            o2 += w3v[dr] * a.z; o3 += w3v[dr] * a.w;
        }
        union { uint2 u; _Float16 h[4]; } pk;
        pk.h[0] = (_Float16)o0; pk.h[1] = (_Float16)o1;
        pk.h[2] = (_Float16)o2; pk.h[3] = (_Float16)o3;
        *(uint2*)&y3p[wv][r3 * 32 + cb] = pk.u;
    }
    __syncthreads();

    // ---- transpose 4 planes -> global [b][cg][hw][4], 8B/px stores
    _Float16* og = y3g + (size_t)(b * 24 + cg) * HW_ * 4;
#pragma unroll
    for (int i = 0; i < 2; ++i) {
        int p = i * 256 + tid;
        union { uint2 u; unsigned short h[4]; } pk;
#pragma unroll
        for (int j = 0; j < 4; ++j)
            pk.h[j] = *(const unsigned short*)&y3p[j][p];
        int oh = p >> 5, ow = p & 31;
        size_t hw = (size_t)((bh0 + oh) << 8) + bw0 + ow;
        *(uint2*)&og[hw * 4] = pk.u;
    }
}

// ---------------------------------------------------------------------------
// K3: pointwise 96x96 fp16 MFMA GEMM + fp32 gate. B-frags = 2x f16x4 loads
// from the pixel-major [b][cg24][hw][4] y3 layout.
// ---------------------------------------------------------------------------
#define PWS 104

__global__ __launch_bounds__(256) void k_pw(
    const _Float16* __restrict__ y3, const float* __restrict__ fea,
    const float2* __restrict__ stats,
    const float* __restrict__ gamma, const float* __restrict__ beta,
    const float* __restrict__ pw, float* __restrict__ out)
{
    __shared__ _Float16 pwl[C_ * PWS];
    const int tid = threadIdx.x;

#pragma unroll 1
    for (int i = 0; i < 18; ++i) {
        int f = (i * 256 + tid) * 2;
        float2 v = *(const float2*)(pw + f);
        int c = f / 96, k = f - c * 96;
        union { unsigned u; _Float16 h[2]; } pk;
        pk.h[0] = (_Float16)v.x; pk.h[1] = (_Float16)v.y;
        *(unsigned*)&pwl[c * PWS + k] = pk.u;
    }
    __syncthreads();

    const int lane = tid & 63, wv = tid >> 6;
    const int lg = lane >> 4, lc = lane & 15;
    const int b  = blockIdx.y;
    const int p0 = blockIdx.x * 256 + wv * 64;
    const _Float16* yb = y3 + (size_t)b * 24 * HW_ * 4;

    f32x4 acc[6][4];
#pragma unroll
    for (int m = 0; m < 6; ++m)
#pragma unroll
        for (int n = 0; n < 4; ++n) acc[m][n] = (f32x4){0.f, 0.f, 0.f, 0.f};

#pragma unroll
    for (int ks = 0; ks < 3; ++ks) {
        f16x8 af[6];
#pragma unroll
        for (int m = 0; m < 6; ++m)
            af[m] = *(const f16x8*)&pwl[(m * 16 + lc) * PWS + ks * 32 + lg * 8];
        int g0 = ks * 8 + lg * 2;
#pragma unroll
        for (int nf = 0; nf < 4; ++nf) {
            size_t px = (size_t)p0 + nf * 16 + lc;
            union { f16x8 v; f16x4 h[2]; } bf;
            bf.h[0] = *(const f16x4*)&yb[((size_t)g0 * HW_ + px) * 4];
            bf.h[1] = *(const f16x4*)&yb[((size_t)(g0 + 1) * HW_ + px) * 4];
#pragma unroll
            for (int m = 0; m < 6; ++m)
                acc[m][nf] = __builtin_amdgcn_mfma_f32_16x16x32_f16(af[m], bf.v, acc[m][nf], 0, 0, 0);
        }
    }

    float2 st[4];
#pragma unroll
    for (int nf = 0; nf < 4; ++nf)
        st[nf] = stats[(size_t)b * HW_ + p0 + nf * 16 + lc];

#pragma unroll
    for (int m = 0; m < 6; ++m) {
#pragma unroll
        for (int r = 0; r < 4; ++r) {
            int c = m * 16 + lg * 4 + r;
            float gm = gamma[c], btv = beta[c];
            const float* fp = fea + ((size_t)b * C_ + c) * HW_ + p0 + lc;
            float*       op = out + ((size_t)b * C_ + c) * HW_ + p0 + lc;
#pragma unroll
            for (int nf = 0; nf < 4; ++nf) {
                float xv = (fp[nf * 16] - st[nf].x) * st[nf].y * gm + btv;
                op[nf * 16] = acc[m][nf][r] * xv;
            }
        }
    }
}

extern "C" void kernel_launch(void* const* d_in, const int* in_sizes, int n_in,
                              void* d_out, int out_size, void* d_ws, size_t ws_size,
                              hipStream_t stream) {
    const float* fea   = (const float*)d_in[0];
    const float* gamma = (const float*)d_in[1];
    const float* beta  = (const float*)d_in[2];
    const float* w1    = (const float*)d_in[3];
    const float* b1    = (const float*)d_in[4];
    const float* w2    = (const float*)d_in[5];
    const float* b2    = (const float*)d_in[6];
    const float* w3    = (const float*)d_in[7];
    const float* b3    = (const float*)d_in[8];
    const float* pw    = (const float*)d_in[9];
    float* out = (float*)d_out;

    _Float16* y3buf = (_Float16*)d_ws;                                    // 100.66 MB
    float*    statp = (float*)((char*)d_ws + (size_t)B_ * C_ * HW_ * 2);  // +4.19 MB

    k_stats<<<dim3(B_ * HW_ / 1024), 256, 0, stream>>>(fea, (float4*)statp);
    k_dw<<<dim3(W_ / 32, H_ / 16, 24 * B_), 256, 0, stream>>>(
        fea, (const float2*)statp, gamma, beta, w1, b1, w2, b2, w3, b3, y3buf);
    k_pw<<<dim3(HW_ / 256, B_), 256, 0, stream>>>(
        y3buf, fea, (const float2*)statp, gamma, beta, pw, out);
}